// Round 2
// baseline (312.167 us; speedup 1.0000x reference)
//
#include <hip/hip_runtime.h>

// Problem constants (fixed-shape problem):
// h: (2,1,1,16,16) fp32   = 512
// gi: (2,M,1,16)   fp32   (e = gi[0], f = gi[1], row-major m*16+i)
// gj: (2,1,M,16)   fp32   (a = gj[0], b = gj[1], row-major m*16+j)
// theta: (2,M)     fp32
// out: (2,16,16)   fp32   = 512 (re block then im block)

constexpr int MDIM    = 524288;
constexpr int THREADS = 256;
constexpr int BLOCKS  = 2048;                     // 8 blocks/CU, 32 waves/CU (100% occ at 64 VGPR)
constexpr int SLOTS   = BLOCKS * THREADS / 16;    // 32768 m-slots; MDIM/(2*SLOTS) = 8 iters

__device__ __forceinline__ void theta_step(
    const float4 e4, const float4 f4, const float4 a4, const float4 b4,
    const float c, const float s,
    float (&are)[4][4], float (&aim)[4][4])
{
    const float av[4] = {a4.x, a4.y, a4.z, a4.w};
    const float bv[4] = {b4.x, b4.y, b4.z, b4.w};
    const float ev[4] = {e4.x, e4.y, e4.z, e4.w};
    const float fv[4] = {f4.x, f4.y, f4.z, f4.w};
    float ure[4], uim[4];
#pragma unroll
    for (int j = 0; j < 4; ++j) {
        ure[j] = av[j] * c - bv[j] * s;   // u_re = a*cos(t0) - b*sin(t1)
        uim[j] = av[j] * s + bv[j] * c;   // u_im = a*sin(t1) + b*cos(t0)
    }
#pragma unroll
    for (int i = 0; i < 4; ++i) {
#pragma unroll
        for (int j = 0; j < 4; ++j) {
            are[i][j] += ev[i] * ure[j] - fv[i] * uim[j];
            aim[i][j] += ev[i] * uim[j] + fv[i] * ure[j];
        }
    }
}

// Shared main-loop body; Fold to 512 block-partials in `red`.
template <bool USE_ATOMIC>
__device__ __forceinline__ void theta_body(
    const float* __restrict__ gi, const float* __restrict__ gj,
    const float* __restrict__ theta, float* __restrict__ dst /* partial or out */)
{
    const int t    = threadIdx.x;
    const int g    = blockIdx.x * THREADS + t;
    const int tile = t & 15;                 // 16 tiles of 4x4 cover 16x16
    const int i0   = (tile >> 2) << 2;
    const int j0   = (tile & 3) << 2;
    const int slot = g >> 4;                 // lane bits 4,5 give wave m-parallelism

    const float* e_base = gi + i0;
    const float* f_base = gi + MDIM * 16 + i0;
    const float* a_base = gj + j0;
    const float* b_base = gj + MDIM * 16 + j0;

    float are[4][4] = {{0.f}};
    float aim[4][4] = {{0.f}};

    for (int m = slot; m < MDIM; m += 2 * SLOTS) {
        const int m2 = m + SLOTS;
        const float4 e0 = *(const float4*)(e_base + m * 16);
        const float4 f0 = *(const float4*)(f_base + m * 16);
        const float4 a0 = *(const float4*)(a_base + m * 16);
        const float4 b0 = *(const float4*)(b_base + m * 16);
        const float t00 = theta[m];
        const float t10 = theta[MDIM + m];
        const float4 e1 = *(const float4*)(e_base + m2 * 16);
        const float4 f1 = *(const float4*)(f_base + m2 * 16);
        const float4 a1 = *(const float4*)(a_base + m2 * 16);
        const float4 b1 = *(const float4*)(b_base + m2 * 16);
        const float t01 = theta[m2];
        const float t11 = theta[MDIM + m2];

        const float c0 = __cosf(t00), s0 = __sinf(t10);
        theta_step(e0, f0, a0, b0, c0, s0, are, aim);
        const float c1 = __cosf(t01), s1 = __sinf(t11);
        theta_step(e1, f1, a1, b1, c1, s1, are, aim);
    }

    // Fold the 4 m-lanes (lane bits 4,5) via butterfly shuffles.
#pragma unroll
    for (int i = 0; i < 4; ++i) {
#pragma unroll
        for (int j = 0; j < 4; ++j) {
            are[i][j] += __shfl_xor(are[i][j], 16);
            are[i][j] += __shfl_xor(are[i][j], 32);
            aim[i][j] += __shfl_xor(aim[i][j], 16);
            aim[i][j] += __shfl_xor(aim[i][j], 32);
        }
    }

    // Fold the 4 waves via LDS.
    __shared__ float red[4][16][33];
    const int wave = t >> 6;
    const int lane = t & 63;
    if (lane < 16) {
#pragma unroll
        for (int i = 0; i < 4; ++i) {
#pragma unroll
            for (int j = 0; j < 4; ++j) {
                red[wave][lane][i * 4 + j]      = are[i][j];
                red[wave][lane][16 + i * 4 + j] = aim[i][j];
            }
        }
    }
    __syncthreads();

    // 512 entries (16 tiles x 32 values); each thread finishes 2.
#pragma unroll
    for (int k = 0; k < 2; ++k) {
        const int idx = t * 2 + k;
        const int tl  = idx >> 5;
        const int v   = idx & 31;
        const float sum = red[0][tl][v] + red[1][tl][v] + red[2][tl][v] + red[3][tl][v];
        const int ii  = ((tl >> 2) << 2) + ((v & 15) >> 2);
        const int jj  = ((tl & 3) << 2) + (v & 3);
        const int off = ((v & 16) ? 256 : 0) + ii * 16 + jj;
        if (USE_ATOMIC) atomicAdd(dst + off, sum);
        else            dst[blockIdx.x * 512 + off] = sum;
    }
}

__global__ __launch_bounds__(THREADS, 8) void theta_main_ws(
    const float* __restrict__ gi, const float* __restrict__ gj,
    const float* __restrict__ theta, float* __restrict__ partial)
{
    theta_body<false>(gi, gj, theta, partial);
}

__global__ __launch_bounds__(THREADS, 8) void theta_main_atomic(
    const float* __restrict__ gi, const float* __restrict__ gj,
    const float* __restrict__ theta, float* __restrict__ out)
{
    theta_body<true>(gi, gj, theta, out);
}

// Stage 2: one wave per output element; fold BLOCKS partials + h bias.
__global__ __launch_bounds__(256) void theta_reduce(
    const float* __restrict__ h, const float* __restrict__ partial,
    float* __restrict__ out)
{
    const int w    = (blockIdx.x * 256 + threadIdx.x) >> 6;  // output index 0..511
    const int lane = threadIdx.x & 63;
    float s = 0.f;
#pragma unroll 8
    for (int j = 0; j < BLOCKS / 64; ++j)
        s += partial[(j * 64 + lane) * 512 + w];
#pragma unroll
    for (int d = 1; d < 64; d <<= 1) s += __shfl_xor(s, d);
    if (lane == 0) out[w] = h[w] + s;
}

__global__ void theta_init(const float* __restrict__ h, float* __restrict__ out) {
    int k = blockIdx.x * blockDim.x + threadIdx.x;
    if (k < 512) out[k] = h[k];
}

extern "C" void kernel_launch(void* const* d_in, const int* in_sizes, int n_in,
                              void* d_out, int out_size, void* d_ws, size_t ws_size,
                              hipStream_t stream) {
    const float* h     = (const float*)d_in[0];
    const float* gi    = (const float*)d_in[1];
    const float* gj    = (const float*)d_in[2];
    const float* theta = (const float*)d_in[3];
    float* out = (float*)d_out;

    const size_t need = (size_t)BLOCKS * 512 * sizeof(float);  // 4 MB of partials
    if (ws_size >= need) {
        float* partial = (float*)d_ws;
        theta_main_ws<<<BLOCKS, THREADS, 0, stream>>>(gi, gj, theta, partial);
        theta_reduce<<<128, 256, 0, stream>>>(h, partial, out);
    } else {
        theta_init<<<2, 256, 0, stream>>>(h, out);
        theta_main_atomic<<<BLOCKS, THREADS, 0, stream>>>(gi, gj, theta, out);
    }
}

// Round 3
// 166.202 us; speedup vs baseline: 1.8782x; 1.8782x over previous
//
#include <hip/hip_runtime.h>

// Problem constants (fixed-shape problem):
// h: (2,1,1,16,16) fp32   = 512
// gi: (2,M,1,16)   fp32   (e = gi[0], f = gi[1], row-major m*16+i)
// gj: (2,1,M,16)   fp32   (a = gj[0], b = gj[1], row-major m*16+j)
// theta: (2,M)     fp32
// out: (2,16,16)   fp32   = 512 (re block then im block)

constexpr int MDIM    = 524288;
constexpr int THREADS = 256;
constexpr int BLOCKS  = 2048;                     // 8 blocks/CU possible at 64 VGPR
constexpr int SLOTS   = BLOCKS * THREADS / 16;    // 32768 m-slots; MDIM/(2*SLOTS) = 8 iters

// NOTE: __launch_bounds__(256,8) forced a 32-VGPR budget -> catastrophic scratch
// spill (WRITE_SIZE 299 MB, 199 us). (256,4) caps at 128 VGPR; body naturally
// compiles to ~64 VGPR (round-1 evidence) so HW can still run 8 waves/SIMD.
#define MAIN_BOUNDS __launch_bounds__(THREADS, 4)

__device__ __forceinline__ void theta_step(
    const float4 e4, const float4 f4, const float4 a4, const float4 b4,
    const float c, const float s,
    float (&are)[4][4], float (&aim)[4][4])
{
    const float av[4] = {a4.x, a4.y, a4.z, a4.w};
    const float bv[4] = {b4.x, b4.y, b4.z, b4.w};
    const float ev[4] = {e4.x, e4.y, e4.z, e4.w};
    const float fv[4] = {f4.x, f4.y, f4.z, f4.w};
    float ure[4], uim[4];
#pragma unroll
    for (int j = 0; j < 4; ++j) {
        ure[j] = av[j] * c - bv[j] * s;   // u_re = a*cos(t0) - b*sin(t1)
        uim[j] = av[j] * s + bv[j] * c;   // u_im = a*sin(t1) + b*cos(t0)
    }
#pragma unroll
    for (int i = 0; i < 4; ++i) {
#pragma unroll
        for (int j = 0; j < 4; ++j) {
            are[i][j] += ev[i] * ure[j] - fv[i] * uim[j];
            aim[i][j] += ev[i] * uim[j] + fv[i] * ure[j];
        }
    }
}

template <bool USE_ATOMIC>
__device__ __forceinline__ void theta_body(
    const float* __restrict__ gi, const float* __restrict__ gj,
    const float* __restrict__ theta, float* __restrict__ dst /* partial or out */)
{
    const int t    = threadIdx.x;
    const int g    = blockIdx.x * THREADS + t;
    const int tile = t & 15;                 // 16 tiles of 4x4 cover 16x16
    const int i0   = (tile >> 2) << 2;
    const int j0   = (tile & 3) << 2;
    const int slot = g >> 4;                 // lane bits 4,5 give wave m-parallelism

    const float* e_base = gi + i0;
    const float* f_base = gi + MDIM * 16 + i0;
    const float* a_base = gj + j0;
    const float* b_base = gj + MDIM * 16 + j0;

    float are[4][4] = {{0.f}};
    float aim[4][4] = {{0.f}};

    for (int m = slot; m < MDIM; m += 2 * SLOTS) {
        const int m2 = m + SLOTS;
        const float4 e0 = *(const float4*)(e_base + m * 16);
        const float4 f0 = *(const float4*)(f_base + m * 16);
        const float4 a0 = *(const float4*)(a_base + m * 16);
        const float4 b0 = *(const float4*)(b_base + m * 16);
        const float t00 = theta[m];
        const float t10 = theta[MDIM + m];
        const float4 e1 = *(const float4*)(e_base + m2 * 16);
        const float4 f1 = *(const float4*)(f_base + m2 * 16);
        const float4 a1 = *(const float4*)(a_base + m2 * 16);
        const float4 b1 = *(const float4*)(b_base + m2 * 16);
        const float t01 = theta[m2];
        const float t11 = theta[MDIM + m2];

        const float c0 = __cosf(t00), s0 = __sinf(t10);
        theta_step(e0, f0, a0, b0, c0, s0, are, aim);
        const float c1 = __cosf(t01), s1 = __sinf(t11);
        theta_step(e1, f1, a1, b1, c1, s1, are, aim);
    }

    // Fold the 4 m-lanes (lane bits 4,5) via butterfly shuffles.
#pragma unroll
    for (int i = 0; i < 4; ++i) {
#pragma unroll
        for (int j = 0; j < 4; ++j) {
            are[i][j] += __shfl_xor(are[i][j], 16);
            are[i][j] += __shfl_xor(are[i][j], 32);
            aim[i][j] += __shfl_xor(aim[i][j], 16);
            aim[i][j] += __shfl_xor(aim[i][j], 32);
        }
    }

    // Fold the 4 waves via LDS.
    __shared__ float red[4][16][33];
    const int wave = t >> 6;
    const int lane = t & 63;
    if (lane < 16) {
#pragma unroll
        for (int i = 0; i < 4; ++i) {
#pragma unroll
            for (int j = 0; j < 4; ++j) {
                red[wave][lane][i * 4 + j]      = are[i][j];
                red[wave][lane][16 + i * 4 + j] = aim[i][j];
            }
        }
    }
    __syncthreads();

    // 512 entries (16 tiles x 32 values); each thread finishes 2.
#pragma unroll
    for (int k = 0; k < 2; ++k) {
        const int idx = t * 2 + k;
        const int tl  = idx >> 5;
        const int v   = idx & 31;
        const float sum = red[0][tl][v] + red[1][tl][v] + red[2][tl][v] + red[3][tl][v];
        const int ii  = ((tl >> 2) << 2) + ((v & 15) >> 2);
        const int jj  = ((tl & 3) << 2) + (v & 3);
        const int off = ((v & 16) ? 256 : 0) + ii * 16 + jj;
        if (USE_ATOMIC) atomicAdd(dst + off, sum);
        else            dst[blockIdx.x * 512 + off] = sum;
    }
}

__global__ MAIN_BOUNDS void theta_main_ws(
    const float* __restrict__ gi, const float* __restrict__ gj,
    const float* __restrict__ theta, float* __restrict__ partial)
{
    theta_body<false>(gi, gj, theta, partial);
}

__global__ MAIN_BOUNDS void theta_main_atomic(
    const float* __restrict__ gi, const float* __restrict__ gj,
    const float* __restrict__ theta, float* __restrict__ out)
{
    theta_body<true>(gi, gj, theta, out);
}

// Stage 2: one wave per output element; fold BLOCKS partials + h bias.
__global__ __launch_bounds__(256) void theta_reduce(
    const float* __restrict__ h, const float* __restrict__ partial,
    float* __restrict__ out)
{
    const int w    = (blockIdx.x * 256 + threadIdx.x) >> 6;  // output index 0..511
    const int lane = threadIdx.x & 63;
    float s = 0.f;
#pragma unroll 8
    for (int j = 0; j < BLOCKS / 64; ++j)
        s += partial[(j * 64 + lane) * 512 + w];
#pragma unroll
    for (int d = 1; d < 64; d <<= 1) s += __shfl_xor(s, d);
    if (lane == 0) out[w] = h[w] + s;
}

__global__ void theta_init(const float* __restrict__ h, float* __restrict__ out) {
    int k = blockIdx.x * blockDim.x + threadIdx.x;
    if (k < 512) out[k] = h[k];
}

extern "C" void kernel_launch(void* const* d_in, const int* in_sizes, int n_in,
                              void* d_out, int out_size, void* d_ws, size_t ws_size,
                              hipStream_t stream) {
    const float* h     = (const float*)d_in[0];
    const float* gi    = (const float*)d_in[1];
    const float* gj    = (const float*)d_in[2];
    const float* theta = (const float*)d_in[3];
    float* out = (float*)d_out;

    const size_t need = (size_t)BLOCKS * 512 * sizeof(float);  // 4 MB of partials
    if (ws_size >= need) {
        float* partial = (float*)d_ws;
        theta_main_ws<<<BLOCKS, THREADS, 0, stream>>>(gi, gj, theta, partial);
        theta_reduce<<<128, 256, 0, stream>>>(h, partial, out);
    } else {
        theta_init<<<2, 256, 0, stream>>>(h, out);
        theta_main_atomic<<<BLOCKS, THREADS, 0, stream>>>(gi, gj, theta, out);
    }
}

// Round 4
// 165.141 us; speedup vs baseline: 1.8903x; 1.0064x over previous
//
#include <hip/hip_runtime.h>

// Problem constants (fixed-shape problem):
// h: (2,1,1,16,16) fp32   = 512
// gi: (2,M,1,16)   fp32   (e = gi[0], f = gi[1], row-major m*16+i)
// gj: (2,1,M,16)   fp32   (a = gj[0], b = gj[1], row-major m*16+j)
// theta: (2,M)     fp32
// out: (2,16,16)   fp32   = 512 (re block then im block)

constexpr int MDIM    = 524288;
constexpr int THREADS = 256;
constexpr int BLOCKS  = 2048;                     // 8 blocks/CU at 64 VGPR
constexpr int SLOTS   = BLOCKS * THREADS / 16;    // 32768 m-slots; MDIM/(2*SLOTS) = 8 iters

// Occupancy history:
//  (256,8) -> compiler forced 32 VGPR -> 299 MB scratch spill, 199 us.  [R2]
//  (256,4) -> 64 VGPR, no spill, but OccupancyPercent pinned at 33%
//             (= 4 blocks/CU = the "4" arg acting as a residency MAX). [R3]
//  Now: min 4 (keeps the proven 64-VGPR codegen), max 8 (allow 8 waves/EU).
#define MAIN_BOUNDS __launch_bounds__(THREADS) __attribute__((amdgpu_waves_per_eu(4, 8)))

__device__ __forceinline__ void theta_step(
    const float4 e4, const float4 f4, const float4 a4, const float4 b4,
    const float c, const float s,
    float (&are)[4][4], float (&aim)[4][4])
{
    const float av[4] = {a4.x, a4.y, a4.z, a4.w};
    const float bv[4] = {b4.x, b4.y, b4.z, b4.w};
    const float ev[4] = {e4.x, e4.y, e4.z, e4.w};
    const float fv[4] = {f4.x, f4.y, f4.z, f4.w};
    float ure[4], uim[4];
#pragma unroll
    for (int j = 0; j < 4; ++j) {
        ure[j] = av[j] * c - bv[j] * s;   // u_re = a*cos(t0) - b*sin(t1)
        uim[j] = av[j] * s + bv[j] * c;   // u_im = a*sin(t1) + b*cos(t0)
    }
#pragma unroll
    for (int i = 0; i < 4; ++i) {
#pragma unroll
        for (int j = 0; j < 4; ++j) {
            are[i][j] += ev[i] * ure[j] - fv[i] * uim[j];
            aim[i][j] += ev[i] * uim[j] + fv[i] * ure[j];
        }
    }
}

template <bool USE_ATOMIC>
__device__ __forceinline__ void theta_body(
    const float* __restrict__ gi, const float* __restrict__ gj,
    const float* __restrict__ theta, float* __restrict__ dst /* partial or out */)
{
    const int t    = threadIdx.x;
    const int g    = blockIdx.x * THREADS + t;
    const int tile = t & 15;                 // 16 tiles of 4x4 cover 16x16
    const int i0   = (tile >> 2) << 2;
    const int j0   = (tile & 3) << 2;
    const int slot = g >> 4;                 // lane bits 4,5 give wave m-parallelism

    const float* e_base = gi + i0;
    const float* f_base = gi + MDIM * 16 + i0;
    const float* a_base = gj + j0;
    const float* b_base = gj + MDIM * 16 + j0;

    float are[4][4] = {{0.f}};
    float aim[4][4] = {{0.f}};

    for (int m = slot; m < MDIM; m += 2 * SLOTS) {
        const int m2 = m + SLOTS;
        const float4 e0 = *(const float4*)(e_base + m * 16);
        const float4 f0 = *(const float4*)(f_base + m * 16);
        const float4 a0 = *(const float4*)(a_base + m * 16);
        const float4 b0 = *(const float4*)(b_base + m * 16);
        const float t00 = theta[m];
        const float t10 = theta[MDIM + m];
        const float4 e1 = *(const float4*)(e_base + m2 * 16);
        const float4 f1 = *(const float4*)(f_base + m2 * 16);
        const float4 a1 = *(const float4*)(a_base + m2 * 16);
        const float4 b1 = *(const float4*)(b_base + m2 * 16);
        const float t01 = theta[m2];
        const float t11 = theta[MDIM + m2];

        const float c0 = __cosf(t00), s0 = __sinf(t10);
        theta_step(e0, f0, a0, b0, c0, s0, are, aim);
        const float c1 = __cosf(t01), s1 = __sinf(t11);
        theta_step(e1, f1, a1, b1, c1, s1, are, aim);
    }

    // Fold the 4 m-lanes (lane bits 4,5) via butterfly shuffles.
#pragma unroll
    for (int i = 0; i < 4; ++i) {
#pragma unroll
        for (int j = 0; j < 4; ++j) {
            are[i][j] += __shfl_xor(are[i][j], 16);
            are[i][j] += __shfl_xor(are[i][j], 32);
            aim[i][j] += __shfl_xor(aim[i][j], 16);
            aim[i][j] += __shfl_xor(aim[i][j], 32);
        }
    }

    // Fold the 4 waves via LDS.
    __shared__ float red[4][16][33];
    const int wave = t >> 6;
    const int lane = t & 63;
    if (lane < 16) {
#pragma unroll
        for (int i = 0; i < 4; ++i) {
#pragma unroll
            for (int j = 0; j < 4; ++j) {
                red[wave][lane][i * 4 + j]      = are[i][j];
                red[wave][lane][16 + i * 4 + j] = aim[i][j];
            }
        }
    }
    __syncthreads();

    // 512 entries (16 tiles x 32 values); each thread finishes 2.
#pragma unroll
    for (int k = 0; k < 2; ++k) {
        const int idx = t * 2 + k;
        const int tl  = idx >> 5;
        const int v   = idx & 31;
        const float sum = red[0][tl][v] + red[1][tl][v] + red[2][tl][v] + red[3][tl][v];
        const int ii  = ((tl >> 2) << 2) + ((v & 15) >> 2);
        const int jj  = ((tl & 3) << 2) + (v & 3);
        const int off = ((v & 16) ? 256 : 0) + ii * 16 + jj;
        if (USE_ATOMIC) atomicAdd(dst + off, sum);
        else            dst[blockIdx.x * 512 + off] = sum;
    }
}

__global__ MAIN_BOUNDS void theta_main_ws(
    const float* __restrict__ gi, const float* __restrict__ gj,
    const float* __restrict__ theta, float* __restrict__ partial)
{
    theta_body<false>(gi, gj, theta, partial);
}

__global__ MAIN_BOUNDS void theta_main_atomic(
    const float* __restrict__ gi, const float* __restrict__ gj,
    const float* __restrict__ theta, float* __restrict__ out)
{
    theta_body<true>(gi, gj, theta, out);
}

// Stage 2: one wave per output element; fold BLOCKS partials + h bias.
__global__ __launch_bounds__(256) void theta_reduce(
    const float* __restrict__ h, const float* __restrict__ partial,
    float* __restrict__ out)
{
    const int w    = (blockIdx.x * 256 + threadIdx.x) >> 6;  // output index 0..511
    const int lane = threadIdx.x & 63;
    float s = 0.f;
#pragma unroll 8
    for (int j = 0; j < BLOCKS / 64; ++j)
        s += partial[(j * 64 + lane) * 512 + w];
#pragma unroll
    for (int d = 1; d < 64; d <<= 1) s += __shfl_xor(s, d);
    if (lane == 0) out[w] = h[w] + s;
}

__global__ void theta_init(const float* __restrict__ h, float* __restrict__ out) {
    int k = blockIdx.x * blockDim.x + threadIdx.x;
    if (k < 512) out[k] = h[k];
}

extern "C" void kernel_launch(void* const* d_in, const int* in_sizes, int n_in,
                              void* d_out, int out_size, void* d_ws, size_t ws_size,
                              hipStream_t stream) {
    const float* h     = (const float*)d_in[0];
    const float* gi    = (const float*)d_in[1];
    const float* gj    = (const float*)d_in[2];
    const float* theta = (const float*)d_in[3];
    float* out = (float*)d_out;

    const size_t need = (size_t)BLOCKS * 512 * sizeof(float);  // 4 MB of partials
    if (ws_size >= need) {
        float* partial = (float*)d_ws;
        theta_main_ws<<<BLOCKS, THREADS, 0, stream>>>(gi, gj, theta, partial);
        theta_reduce<<<128, 256, 0, stream>>>(h, partial, out);
    } else {
        theta_init<<<2, 256, 0, stream>>>(h, out);
        theta_main_atomic<<<BLOCKS, THREADS, 0, stream>>>(gi, gj, theta, out);
    }
}

// Round 5
// 163.394 us; speedup vs baseline: 1.9105x; 1.0107x over previous
//
#include <hip/hip_runtime.h>

// Problem constants (fixed-shape problem):
// h: (2,1,1,16,16) fp32   = 512
// gi: (2,M,1,16)   fp32   (e = gi[0], f = gi[1], row-major m*16+i)
// gj: (2,1,M,16)   fp32   (a = gj[0], b = gj[1], row-major m*16+j)
// theta: (2,M)     fp32
// out: (2,16,16)   fp32   = 512 (re block then im block)
//
// Occupancy history:
//  R2: __launch_bounds__(256,8) -> compiler forced 32 VGPR (=256/8: per-SIMD
//      pool is 256 wave-regs) -> 299 MB scratch spill, 199 us.
//  R3/R4: 64 VGPR -> 4 waves/SIMD (256/64), 33% occ, 48 us. TLP is capped.
//  This round: keep 4 waves/SIMD but (a) v_pk_fma_f32 fp32 (2x issue rate),
//  (b) global_load_lds double-buffered staging so load latency costs no VGPRs.

constexpr int MDIM    = 524288;
constexpr int THREADS = 256;
constexpr int BLOCKS  = 1024;                    // 4 blocks/CU (LDS-pinned), no tail
constexpr int M_PER_B = MDIM / BLOCKS;           // 512 m per block
constexpr int CHUNK   = 64;                      // m per staged chunk
constexpr int NCHUNK  = M_PER_B / CHUNK;         // 8
// LDS buffer layout (floats): e[1024] f[1024] a[1024] b[1024] t0[64] t1[64]
constexpr int T0_OFF  = 4096;
constexpr int T1_OFF  = 4160;
constexpr int BUF_F   = 4224;                    // floats per buffer (16896 B)

typedef float f32x2 __attribute__((ext_vector_type(2)));

#define AS1 __attribute__((address_space(1)))
#define AS3 __attribute__((address_space(3)))

__device__ __forceinline__ void cp16(const float* g, float* l) {
    __builtin_amdgcn_global_load_lds((const AS1 void*)g, (AS3 void*)l, 16, 0, 0);
}
__device__ __forceinline__ void cp4(const float* g, float* l) {
    __builtin_amdgcn_global_load_lds((const AS1 void*)g, (AS3 void*)l, 4, 0, 0);
}

// Wave w stages one 4 KB array (w=0:e, 1:f, 2:a, 3:b); wave 0 also theta.
__device__ __forceinline__ void stage_chunk(
    const float* __restrict__ gi, const float* __restrict__ gj,
    const float* __restrict__ theta, float* buf, int m0, int wave, int lane)
{
    const float* gsrc;
    if      (wave == 0) gsrc = gi + (size_t)m0 * 16;
    else if (wave == 1) gsrc = gi + (size_t)MDIM * 16 + (size_t)m0 * 16;
    else if (wave == 2) gsrc = gj + (size_t)m0 * 16;
    else                gsrc = gj + (size_t)MDIM * 16 + (size_t)m0 * 16;
    float* ldst = buf + wave * 1024;
#pragma unroll
    for (int j = 0; j < 4; ++j) {
        // lane's 16B: global = gsrc + j*1KB + lane*16B; LDS dest = uniform base,
        // HW appends lane*16 (wave-uniform-base semantics).
        cp16(gsrc + j * 256 + lane * 4, ldst + j * 256);
    }
    if (wave == 0) {
        cp4(theta + m0 + lane,        buf + T0_OFF);
        cp4(theta + MDIM + m0 + lane, buf + T1_OFF);
    }
}

__device__ __forceinline__ void compute_chunk(
    const float* buf, int slot, int i0, int j0,
    f32x2 (&are)[4][2], f32x2 (&aim)[4][2])
{
#pragma unroll
    for (int k = 0; k < 4; ++k) {
        const int ml = slot + 16 * k;            // 16 m's in parallel, 4 steps
        const float4 e4 = *(const float4*)(buf +        ml * 16 + i0);
        const float4 f4 = *(const float4*)(buf + 1024 + ml * 16 + i0);
        const float4 a4 = *(const float4*)(buf + 2048 + ml * 16 + j0);
        const float4 b4 = *(const float4*)(buf + 3072 + ml * 16 + j0);
        const float c = __cosf(buf[T0_OFF + ml]);
        const float s = __sinf(buf[T1_OFF + ml]);
        const f32x2 cc = {c, c}, ss = {s, s};
        const f32x2 a01 = {a4.x, a4.y}, a23 = {a4.z, a4.w};
        const f32x2 b01 = {b4.x, b4.y}, b23 = {b4.z, b4.w};
        f32x2 ure[2], uim[2];
        ure[0] = __builtin_elementwise_fma(-b01, ss, a01 * cc);  // a*c - b*s
        ure[1] = __builtin_elementwise_fma(-b23, ss, a23 * cc);
        uim[0] = __builtin_elementwise_fma( b01, cc, a01 * ss);  // a*s + b*c
        uim[1] = __builtin_elementwise_fma( b23, cc, a23 * ss);
        const float ev[4] = {e4.x, e4.y, e4.z, e4.w};
        const float fv[4] = {f4.x, f4.y, f4.z, f4.w};
#pragma unroll
        for (int i = 0; i < 4; ++i) {
            const f32x2 ee = {ev[i], ev[i]};
            const f32x2 ff = {fv[i], fv[i]};
#pragma unroll
            for (int jp = 0; jp < 2; ++jp) {
                are[i][jp] = __builtin_elementwise_fma( ee, ure[jp], are[i][jp]);
                are[i][jp] = __builtin_elementwise_fma(-ff, uim[jp], are[i][jp]);
                aim[i][jp] = __builtin_elementwise_fma( ee, uim[jp], aim[i][jp]);
                aim[i][jp] = __builtin_elementwise_fma( ff, ure[jp], aim[i][jp]);
            }
        }
    }
}

template <bool USE_ATOMIC>
__device__ __forceinline__ void theta_body(
    const float* __restrict__ gi, const float* __restrict__ gj,
    const float* __restrict__ theta, float* __restrict__ dst)
{
    __shared__ float smem[2 * BUF_F];            // 33792 B -> 4 blocks/CU
    const int t    = threadIdx.x;
    const int wave = t >> 6;
    const int lane = t & 63;
    const int slot = t >> 4;                     // wave-local m slots = lane bits 4,5
    const int tile = t & 15;
    const int i0   = (tile >> 2) << 2;
    const int j0   = (tile & 3) << 2;
    const int m_base = blockIdx.x * M_PER_B;

    f32x2 are[4][2], aim[4][2];
#pragma unroll
    for (int i = 0; i < 4; ++i)
#pragma unroll
        for (int jp = 0; jp < 2; ++jp) { are[i][jp] = {0.f, 0.f}; aim[i][jp] = {0.f, 0.f}; }

    stage_chunk(gi, gj, theta, smem, m_base, wave, lane);
    for (int c = 0; c < NCHUNK; ++c) {
        __syncthreads();                         // chunk c staging complete (vmcnt drain)
        if (c + 1 < NCHUNK)
            stage_chunk(gi, gj, theta, smem + ((c + 1) & 1) * BUF_F,
                        m_base + (c + 1) * CHUNK, wave, lane);   // overlaps compute(c)
        compute_chunk(smem + (c & 1) * BUF_F, slot & 3 ? slot : slot, i0, j0, are, aim);
    }

    // Unpack f32x2 accumulators to scalars: j = jp*2 + half.
    float sre[4][4], sim[4][4];
#pragma unroll
    for (int i = 0; i < 4; ++i)
#pragma unroll
        for (int jp = 0; jp < 2; ++jp) {
            sre[i][jp * 2]     = are[i][jp].x;  sre[i][jp * 2 + 1] = are[i][jp].y;
            sim[i][jp * 2]     = aim[i][jp].x;  sim[i][jp * 2 + 1] = aim[i][jp].y;
        }

    // Fold the 4 m-lanes (lane bits 4,5) via butterfly shuffles.
#pragma unroll
    for (int i = 0; i < 4; ++i)
#pragma unroll
        for (int j = 0; j < 4; ++j) {
            sre[i][j] += __shfl_xor(sre[i][j], 16);
            sre[i][j] += __shfl_xor(sre[i][j], 32);
            sim[i][j] += __shfl_xor(sim[i][j], 16);
            sim[i][j] += __shfl_xor(sim[i][j], 32);
        }

    // Fold the 4 waves via LDS; reuse smem[0..2112) (buf0 dead: last compute
    // used buf1, and the c=7 barrier retired all buf0 readers).
    float (*red)[16][33] = (float (*)[16][33])smem;
    if (lane < 16) {
#pragma unroll
        for (int i = 0; i < 4; ++i)
#pragma unroll
            for (int j = 0; j < 4; ++j) {
                red[wave][lane][i * 4 + j]      = sre[i][j];
                red[wave][lane][16 + i * 4 + j] = sim[i][j];
            }
    }
    __syncthreads();

#pragma unroll
    for (int k = 0; k < 2; ++k) {
        const int idx = t * 2 + k;
        const int tl  = idx >> 5;
        const int v   = idx & 31;
        const float sum = red[0][tl][v] + red[1][tl][v] + red[2][tl][v] + red[3][tl][v];
        const int ii  = ((tl >> 2) << 2) + ((v & 15) >> 2);
        const int jj  = ((tl & 3) << 2) + (v & 3);
        const int off = ((v & 16) ? 256 : 0) + ii * 16 + jj;
        if (USE_ATOMIC) atomicAdd(dst + off, sum);
        else            dst[blockIdx.x * 512 + off] = sum;
    }
}

__global__ __launch_bounds__(THREADS, 4) void theta_main_ws(
    const float* __restrict__ gi, const float* __restrict__ gj,
    const float* __restrict__ theta, float* __restrict__ partial)
{
    theta_body<false>(gi, gj, theta, partial);
}

__global__ __launch_bounds__(THREADS, 4) void theta_main_atomic(
    const float* __restrict__ gi, const float* __restrict__ gj,
    const float* __restrict__ theta, float* __restrict__ out)
{
    theta_body<true>(gi, gj, theta, out);
}

// Stage 2: one wave per output element; fold BLOCKS partials + h bias.
__global__ __launch_bounds__(256) void theta_reduce(
    const float* __restrict__ h, const float* __restrict__ partial,
    float* __restrict__ out)
{
    const int w    = (blockIdx.x * 256 + threadIdx.x) >> 6;  // output index 0..511
    const int lane = threadIdx.x & 63;
    float s = 0.f;
#pragma unroll 4
    for (int j = 0; j < BLOCKS / 64; ++j)
        s += partial[(size_t)(j * 64 + lane) * 512 + w];
#pragma unroll
    for (int d = 1; d < 64; d <<= 1) s += __shfl_xor(s, d);
    if (lane == 0) out[w] = h[w] + s;
}

__global__ void theta_init(const float* __restrict__ h, float* __restrict__ out) {
    int k = blockIdx.x * blockDim.x + threadIdx.x;
    if (k < 512) out[k] = h[k];
}

extern "C" void kernel_launch(void* const* d_in, const int* in_sizes, int n_in,
                              void* d_out, int out_size, void* d_ws, size_t ws_size,
                              hipStream_t stream) {
    const float* h     = (const float*)d_in[0];
    const float* gi    = (const float*)d_in[1];
    const float* gj    = (const float*)d_in[2];
    const float* theta = (const float*)d_in[3];
    float* out = (float*)d_out;

    const size_t need = (size_t)BLOCKS * 512 * sizeof(float);  // 2 MB of partials
    if (ws_size >= need) {
        float* partial = (float*)d_ws;
        theta_main_ws<<<BLOCKS, THREADS, 0, stream>>>(gi, gj, theta, partial);
        theta_reduce<<<128, 256, 0, stream>>>(h, partial, out);
    } else {
        theta_init<<<2, 256, 0, stream>>>(h, out);
        theta_main_atomic<<<BLOCKS, THREADS, 0, stream>>>(gi, gj, theta, out);
    }
}

// Round 7
// 160.984 us; speedup vs baseline: 1.9391x; 1.0150x over previous
//
#include <hip/hip_runtime.h>

// h: (2,1,1,16,16) fp32 | gi: (2,M,16) | gj: (2,M,16) | theta: (2,M) | out: (2,16,16)
//
// History: R2 32-VGPR spill (299 MB scratch, 199us). R3/R4 VGPR-loads 48us
// (4 waves/SIMD cap, latency-exposed). R5 barrier-coupled LDS dbuf 53us
// (vmcnt(0) drain per chunk; packed FMA halved compute -> LESS latency hidden).
// R6 crashed: 67.5 KB static LDS (>64 KB limit) and/or raw-imm s_waitcnt.
// R7 = R6 architecture, fixed: DEPTH=3 (50688 B LDS), inline-asm vmcnt literals.
// Per-wave PRIVATE staging, no K-loop barriers, 12 loads (8.5 KB) always in
// flight per wave; retire-in-order => vmcnt(12) == "oldest chunk landed".

constexpr int MDIM    = 524288;
constexpr int THREADS = 256;
constexpr int BLOCKS  = 512;              // 2 blocks/CU (LDS-pinned)
constexpr int M_PER_B = MDIM / BLOCKS;    // 1024
constexpr int M_PER_W = M_PER_B / 4;      // 256 m per wave
constexpr int CHUNK   = 16;               // m per chunk
constexpr int NCH     = M_PER_W / CHUNK;  // 16 chunks per wave
constexpr int DEPTH   = 3;                // buffers per wave (2 prefetched ahead)

// Per-buffer float offsets: e[256] f[256] a[256] b[256] t0[16] t1[16]
constexpr int E_OFF = 0, F_OFF = 256, A_OFF = 512, B_OFF = 768;
constexpr int T0_OFF = 1024, T1_OFF = 1040;
constexpr int BUF_F  = 1056;
constexpr int WAVE_F = DEPTH * BUF_F;     // 3168 floats per wave
constexpr int SMEM_F = 4 * WAVE_F;        // 12672 floats = 50688 B
static_assert(SMEM_F * sizeof(float) <= 65536, "LDS must stay under 64 KiB");

typedef float f32x2 __attribute__((ext_vector_type(2)));

#define AS1 __attribute__((address_space(1)))
#define AS3 __attribute__((address_space(3)))

__device__ __forceinline__ void cp16(const float* g, float* l) {
    __builtin_amdgcn_global_load_lds((const AS1 void*)g, (AS3 void*)l, 16, 0, 0);
}
__device__ __forceinline__ void cp4(const float* g, float* l) {
    __builtin_amdgcn_global_load_lds((const AS1 void*)g, (AS3 void*)l, 4, 0, 0);
}

// Stage chunk p into `buf`. Exactly 6 VMEM instructions per call for every
// wave (4 cp16 + 2 exec-masked cp4) — the vmcnt arithmetic depends on this.
__device__ __forceinline__ void stage(
    const float* e_g, const float* f_g, const float* a_g, const float* b_g,
    const float* t0_g, const float* t1_g, float* buf, int p, int lane)
{
    const size_t mo = (size_t)p * (CHUNK * 16);   // 256 floats per chunk
    cp16(e_g + mo, buf + E_OFF);
    cp16(f_g + mo, buf + F_OFF);
    cp16(a_g + mo, buf + A_OFF);
    cp16(b_g + mo, buf + B_OFF);
    if (lane < 16) {
        cp4(t0_g + (size_t)p * CHUNK, buf + T0_OFF);
        cp4(t1_g + (size_t)p * CHUNK, buf + T1_OFF);
    }
}

__device__ __forceinline__ void compute_chunk(
    const float* buf, int slot, int i0, int j0,
    f32x2 (&are)[4][2], f32x2 (&aim)[4][2])
{
#pragma unroll
    for (int k = 0; k < 4; ++k) {
        const int ml = slot + 4 * k;             // 16 m per chunk, 4 per k-step
        const float4 e4 = *(const float4*)(buf + E_OFF + ml * 16 + i0);
        const float4 f4 = *(const float4*)(buf + F_OFF + ml * 16 + i0);
        const float4 a4 = *(const float4*)(buf + A_OFF + ml * 16 + j0);
        const float4 b4 = *(const float4*)(buf + B_OFF + ml * 16 + j0);
        const float c = __cosf(buf[T0_OFF + ml]);
        const float s = __sinf(buf[T1_OFF + ml]);
        const f32x2 cc = {c, c}, ss = {s, s};
        const f32x2 a01 = {a4.x, a4.y}, a23 = {a4.z, a4.w};
        const f32x2 b01 = {b4.x, b4.y}, b23 = {b4.z, b4.w};
        f32x2 ure[2], uim[2];
        ure[0] = __builtin_elementwise_fma(-b01, ss, a01 * cc);  // a*c - b*s
        ure[1] = __builtin_elementwise_fma(-b23, ss, a23 * cc);
        uim[0] = __builtin_elementwise_fma( b01, cc, a01 * ss);  // a*s + b*c
        uim[1] = __builtin_elementwise_fma( b23, cc, a23 * ss);
        const float ev[4] = {e4.x, e4.y, e4.z, e4.w};
        const float fv[4] = {f4.x, f4.y, f4.z, f4.w};
#pragma unroll
        for (int i = 0; i < 4; ++i) {
            const f32x2 ee = {ev[i], ev[i]};
            const f32x2 ff = {fv[i], fv[i]};
#pragma unroll
            for (int jp = 0; jp < 2; ++jp) {
                are[i][jp] = __builtin_elementwise_fma( ee, ure[jp], are[i][jp]);
                are[i][jp] = __builtin_elementwise_fma(-ff, uim[jp], are[i][jp]);
                aim[i][jp] = __builtin_elementwise_fma( ee, uim[jp], aim[i][jp]);
                aim[i][jp] = __builtin_elementwise_fma( ff, ure[jp], aim[i][jp]);
            }
        }
    }
}

template <bool USE_ATOMIC>
__device__ __forceinline__ void theta_body(
    const float* __restrict__ gi, const float* __restrict__ gj,
    const float* __restrict__ theta, float* __restrict__ dst)
{
    __shared__ float smem[SMEM_F];               // 50688 B -> 2 blocks/CU
    const int t    = threadIdx.x;
    const int wave = t >> 6;
    const int lane = t & 63;
    const int slot = (lane >> 4) & 3;            // wave-local m slot (lane bits 4,5)
    const int tile = lane & 15;
    const int i0   = (tile >> 2) << 2;
    const int j0   = (tile & 3) << 2;
    const int m_w0 = blockIdx.x * M_PER_B + wave * M_PER_W;
    float* wbase   = smem + wave * WAVE_F;       // this wave's private region

    // Per-wave global base pointers (lane offset folded in).
    const float* e_g  = gi + (size_t)m_w0 * 16 + lane * 4;
    const float* f_g  = e_g + (size_t)MDIM * 16;
    const float* a_g  = gj + (size_t)m_w0 * 16 + lane * 4;
    const float* b_g  = a_g + (size_t)MDIM * 16;
    const float* t0_g = theta + m_w0 + lane;     // lanes < 16 only
    const float* t1_g = t0_g + MDIM;

    f32x2 are[4][2], aim[4][2];
#pragma unroll
    for (int i = 0; i < 4; ++i)
#pragma unroll
        for (int jp = 0; jp < 2; ++jp) { are[i][jp] = {0.f, 0.f}; aim[i][jp] = {0.f, 0.f}; }

    // Fill: chunks 0,1 in flight (12 loads).
    stage(e_g, f_g, a_g, b_g, t0_g, t1_g, wbase + 0 * BUF_F, 0, lane);
    stage(e_g, f_g, a_g, b_g, t0_g, t1_g, wbase + 1 * BUF_F, 1, lane);

    int sb = 2, cb = 0;
    for (int c = 0; c < NCH - 2; ++c) {
        stage(e_g, f_g, a_g, b_g, t0_g, t1_g, wbase + sb * BUF_F, c + 2, lane);
        sb = (sb == DEPTH - 1) ? 0 : sb + 1;
        // 18 outstanding (chunks c,c+1,c+2); retire-in-order => <=12 means
        // chunk c fully landed. No barrier: this wave is sole producer+consumer.
        asm volatile("s_waitcnt vmcnt(12)" ::: "memory");
        compute_chunk(wbase + cb * BUF_F, slot, i0, j0, are, aim);
        cb = (cb == DEPTH - 1) ? 0 : cb + 1;
    }
    asm volatile("s_waitcnt vmcnt(6)" ::: "memory");
    compute_chunk(wbase + cb * BUF_F, slot, i0, j0, are, aim);
    cb = (cb == DEPTH - 1) ? 0 : cb + 1;
    asm volatile("s_waitcnt vmcnt(0)" ::: "memory");
    compute_chunk(wbase + cb * BUF_F, slot, i0, j0, are, aim);

    // Unpack packed accumulators: j = jp*2 + half.
    float sre[4][4], sim[4][4];
#pragma unroll
    for (int i = 0; i < 4; ++i)
#pragma unroll
        for (int jp = 0; jp < 2; ++jp) {
            sre[i][jp * 2]     = are[i][jp].x;  sre[i][jp * 2 + 1] = are[i][jp].y;
            sim[i][jp * 2]     = aim[i][jp].x;  sim[i][jp * 2 + 1] = aim[i][jp].y;
        }

    // Fold the 4 m-slots (lane bits 4,5).
#pragma unroll
    for (int i = 0; i < 4; ++i)
#pragma unroll
        for (int j = 0; j < 4; ++j) {
            sre[i][j] += __shfl_xor(sre[i][j], 16);
            sre[i][j] += __shfl_xor(sre[i][j], 32);
            sim[i][j] += __shfl_xor(sim[i][j], 16);
            sim[i][j] += __shfl_xor(sim[i][j], 32);
        }

    // Fold the 4 waves via LDS (smem fully consumed; barrier makes reuse safe).
    __syncthreads();
    float (*red)[16][33] = (float (*)[16][33])smem;
    if (lane < 16) {
#pragma unroll
        for (int i = 0; i < 4; ++i)
#pragma unroll
            for (int j = 0; j < 4; ++j) {
                red[wave][lane][i * 4 + j]      = sre[i][j];
                red[wave][lane][16 + i * 4 + j] = sim[i][j];
            }
    }
    __syncthreads();

#pragma unroll
    for (int k = 0; k < 2; ++k) {
        const int idx = t * 2 + k;
        const int tl  = idx >> 5;
        const int v   = idx & 31;
        const float sum = red[0][tl][v] + red[1][tl][v] + red[2][tl][v] + red[3][tl][v];
        const int ii  = ((tl >> 2) << 2) + ((v & 15) >> 2);
        const int jj  = ((tl & 3) << 2) + (v & 3);
        const int off = ((v & 16) ? 256 : 0) + ii * 16 + jj;
        if (USE_ATOMIC) atomicAdd(dst + off, sum);
        else            dst[blockIdx.x * 512 + off] = sum;
    }
}

__global__ __launch_bounds__(THREADS) void theta_main_ws(
    const float* __restrict__ gi, const float* __restrict__ gj,
    const float* __restrict__ theta, float* __restrict__ partial)
{
    theta_body<false>(gi, gj, theta, partial);
}

__global__ __launch_bounds__(THREADS) void theta_main_atomic(
    const float* __restrict__ gi, const float* __restrict__ gj,
    const float* __restrict__ theta, float* __restrict__ out)
{
    theta_body<true>(gi, gj, theta, out);
}

// Stage 2: one wave per output element; fold BLOCKS partials + h bias.
__global__ __launch_bounds__(256) void theta_reduce(
    const float* __restrict__ h, const float* __restrict__ partial,
    float* __restrict__ out)
{
    const int w    = (blockIdx.x * 256 + threadIdx.x) >> 6;  // output index 0..511
    const int lane = threadIdx.x & 63;
    float s = 0.f;
#pragma unroll 4
    for (int j = 0; j < BLOCKS / 64; ++j)
        s += partial[(size_t)(j * 64 + lane) * 512 + w];
#pragma unroll
    for (int d = 1; d < 64; d <<= 1) s += __shfl_xor(s, d);
    if (lane == 0) out[w] = h[w] + s;
}

__global__ void theta_init(const float* __restrict__ h, float* __restrict__ out) {
    int k = blockIdx.x * blockDim.x + threadIdx.x;
    if (k < 512) out[k] = h[k];
}

extern "C" void kernel_launch(void* const* d_in, const int* in_sizes, int n_in,
                              void* d_out, int out_size, void* d_ws, size_t ws_size,
                              hipStream_t stream) {
    const float* h     = (const float*)d_in[0];
    const float* gi    = (const float*)d_in[1];
    const float* gj    = (const float*)d_in[2];
    const float* theta = (const float*)d_in[3];
    float* out = (float*)d_out;

    const size_t need = (size_t)BLOCKS * 512 * sizeof(float);  // 1 MB of partials
    if (ws_size >= need) {
        float* partial = (float*)d_ws;
        theta_main_ws<<<BLOCKS, THREADS, 0, stream>>>(gi, gj, theta, partial);
        theta_reduce<<<128, 256, 0, stream>>>(h, partial, out);
    } else {
        theta_init<<<2, 256, 0, stream>>>(h, out);
        theta_main_atomic<<<BLOCKS, THREADS, 0, stream>>>(gi, gj, theta, out);
    }
}